// Round 17
// baseline (273.780 us; speedup 1.0000x reference)
//
#include <hip/hip_runtime.h>

// GAT forward (2x GATConv + GlobalAttention pool) for MI355X.
// R16: (1) XCD-partitioned edge scatter (range = blockIdx&7 aligns with
// round-robin XCD dispatch; csr write span per XCD = 1.6MB -> L2-resident,
// kills the 16x write-line amplification seen as WRITE_SIZE 67MB);
// (2) gate MFMA fused into pool_partial (per-block, own chunk nodes ->
// no cross-block dep), deleting the gate launch + g round-trip. 7 launches.

constexpr int NN = 50000;          // nodes
constexpr int EE = 800000;         // edges (without self loops)
constexpr int E2 = EE + NN;        // + self loops
constexpr int NG = 64;             // graphs
constexpr float NEG = 0.2f;       // leaky relu slope
constexpr int MT = NN / 16;        // 3125 m-tiles (NN % 16 == 0)
constexpr int SLOTS = 64;          // CSR slots per node; P(deg>64) ~ 0 (Poisson(16)+1)
constexpr int CH = 16;             // pool chunks per graph
constexpr int GB = (MT + 3) / 4;   // gemm blocks (wave per m-tile, 4 waves/block)
constexpr int EDGE_NB = (E2 + 255) / 256;
constexpr int ZERO_NB = (NN + 255) / 256;   // 196
constexpr int RNG = NN / 8;        // 6250 nodes per XCD dst-range

using bf16x8 = __attribute__((ext_vector_type(8))) __bf16;
using f32x4  = __attribute__((ext_vector_type(4))) float;
using f32x2  = __attribute__((ext_vector_type(2))) float;

__device__ __forceinline__ float wred(float v) {
#pragma unroll
  for (int o = 32; o; o >>= 1) v += __shfl_down(v, o);
  return v;
}
__device__ __forceinline__ float sigmoidf(float v) { return 1.f / (1.f + __expf(-v)); }
__device__ __forceinline__ float lrelu(float v) { return fmaxf(v, NEG * v); }
__device__ __forceinline__ unsigned short f2b(float f) {
  union { float f; unsigned u; } v; v.f = f;
  unsigned r = v.u + 0x7fff + ((v.u >> 16) & 1);
  return (unsigned short)(r >> 16);
}
__device__ __forceinline__ float b2f(unsigned short b) {
  union { unsigned u; float f; } v; v.u = ((unsigned)b) << 16;
  return v.f;
}

// ------- prep: zero cnt + pack W1/W2/gateW + graph bounds (one tiny launch) -------
__global__ void prep_kernel(const float* __restrict__ W1, const float* __restrict__ W2,
                            const float* __restrict__ gw1, const float* __restrict__ gamma,
                            const int* __restrict__ batch, int* __restrict__ cnt,
                            unsigned short* __restrict__ W1b, unsigned short* __restrict__ W2b,
                            unsigned short* __restrict__ Bg, int* __restrict__ goffs) {
  int b = blockIdx.x;
  if (b < ZERO_NB) {
    int i = b * 256 + threadIdx.x;
    if (i < NN) cnt[i] = 0;
    return;
  }
  if (b < ZERO_NB + 128) {  // W1 pack: K=128, KC=4, N=256
    int idx = (b - ZERO_NB) * 256 + threadIdx.x;
    int j = idx & 7, lane = (idx >> 3) & 63, rest = idx >> 9;
    int kc = rest & 3, ntile = rest >> 2;
    W1b[idx] = f2b(W1[(kc * 32 + (lane >> 4) * 8 + j) * 256 + ntile * 16 + (lane & 15)]);
    return;
  }
  if (b < ZERO_NB + 192) {  // W2 pack: K=64, KC=2, N=256
    int idx = (b - ZERO_NB - 128) * 256 + threadIdx.x;
    int j = idx & 7, lane = (idx >> 3) & 63, rest = idx >> 9;
    int kc = rest & 1, ntile = rest >> 1;
    W2b[idx] = f2b(W2[(kc * 32 + (lane >> 4) * 8 + j) * 256 + ntile * 16 + (lane & 15)]);
    return;
  }
  if (b < ZERO_NB + 208) {  // gate W pack: K=64, KC=2, N=64, BN scale folded
    int idx = (b - ZERO_NB - 192) * 256 + threadIdx.x;  // 0..4095
    int j = idx & 7, lane = (idx >> 3) & 63, rest = idx >> 9;
    int kc = rest & 1, nt = rest >> 1;
    int k = kc * 32 + (lane >> 4) * 8 + j;
    int n = nt * 16 + (lane & 15);
    Bg[idx] = f2b(gw1[k * 64 + n] * gamma[n] * rsqrtf(1.f + 1e-5f));
    return;
  }
  // graph bounds (sorted batch, binary search)
  int g = threadIdx.x;
  if (g <= NG) {
    int lo = 0, hi = NN;
    while (lo < hi) {
      int mid = (lo + hi) >> 1;
      if (batch[mid] < g) lo = mid + 1; else hi = mid;
    }
    goffs[g] = lo;
  }
}

// ------- MFMA GEMM body + fused attention; C written fp8-e4m3 -------------------
template <int K, bool A32>
__device__ __forceinline__ void gemm_body(int mt, int lane,
                                          const void* __restrict__ A_raw,
                                          const unsigned short* __restrict__ Bp,
                                          unsigned char* __restrict__ C8,
                                          const float* __restrict__ att_s,
                                          const float* __restrict__ att_d,
                                          float* __restrict__ asrc,
                                          float* __restrict__ adst) {
  constexpr int KC = K / 32;
  int m0 = mt * 16;
  int q = lane >> 4, r = lane & 15;
  f32x4 acc[16] = {};
#pragma unroll
  for (int kc = 0; kc < KC; ++kc) {
    bf16x8 a;
    if constexpr (A32) {
      const float* Arow = (const float*)A_raw + (size_t)(m0 + r) * K + q * 8 + kc * 32;
      float4 f0 = *(const float4*)Arow;
      float4 f1 = *(const float4*)(Arow + 4);
      union { bf16x8 v; unsigned short s[8]; } u;
      u.s[0] = f2b(f0.x); u.s[1] = f2b(f0.y); u.s[2] = f2b(f0.z); u.s[3] = f2b(f0.w);
      u.s[4] = f2b(f1.x); u.s[5] = f2b(f1.y); u.s[6] = f2b(f1.z); u.s[7] = f2b(f1.w);
      a = u.v;
    } else {
      a = *(const bf16x8*)((const unsigned short*)A_raw +
                           (size_t)(m0 + r) * K + q * 8 + kc * 32);
    }
#pragma unroll
    for (int nt = 0; nt < 16; ++nt) {
      bf16x8 b = *(const bf16x8*)&Bp[(((size_t)nt * KC + kc) * 64 + lane) * 8];
      acc[nt] = __builtin_amdgcn_mfma_f32_16x16x32_bf16(a, b, acc[nt], 0, 0, 0);
    }
  }
#pragma unroll
  for (int nt = 0; nt < 16; ++nt) {
    unsigned col = nt * 16 + r;
#pragma unroll
    for (int reg = 0; reg < 4; ++reg) {
      unsigned row = m0 + q * 4 + reg;
      int p = __builtin_amdgcn_cvt_pk_fp8_f32(acc[nt][reg], 0.f, 0, false);
      C8[row * 256u + col] = (unsigned char)(p & 0xff);
    }
  }
  float ps[4][4] = {}, pd[4][4] = {};
#pragma unroll
  for (int head = 0; head < 4; ++head) {
#pragma unroll
    for (int i = 0; i < 4; ++i) {
      float sv = att_s[head * 64 + i * 16 + r];
      float dv = att_d[head * 64 + i * 16 + r];
#pragma unroll
      for (int reg = 0; reg < 4; ++reg) {
        ps[head][reg] += acc[head * 4 + i][reg] * sv;
        pd[head][reg] += acc[head * 4 + i][reg] * dv;
      }
    }
  }
#pragma unroll
  for (int head = 0; head < 4; ++head)
#pragma unroll
    for (int reg = 0; reg < 4; ++reg)
#pragma unroll
      for (int o = 1; o < 16; o <<= 1) {
        ps[head][reg] += __shfl_xor(ps[head][reg], o);
        pd[head][reg] += __shfl_xor(pd[head][reg], o);
      }
  if (r == 0) {
#pragma unroll
    for (int reg = 0; reg < 4; ++reg) {
      int row = m0 + q * 4 + reg;
#pragma unroll
      for (int head = 0; head < 4; ++head) {
        asrc[row * 4 + head] = ps[head][reg];
        adst[row * 4 + head] = pd[head][reg];
      }
    }
  }
}

// ------- GEMM1 + XCD-partitioned edge-scatter in ONE launch ---------------------
__global__ void gemm1_build_kernel(const float* __restrict__ x,
                                   const unsigned short* __restrict__ W1b,
                                   unsigned char* __restrict__ C8,
                                   const float* __restrict__ att_s,
                                   const float* __restrict__ att_d,
                                   float* __restrict__ asrc, float* __restrict__ adst,
                                   const int* __restrict__ ei, int* __restrict__ cnt,
                                   int* __restrict__ csr_src) {
  int b = blockIdx.x;
  if (b < GB) {
    int wave = threadIdx.x >> 6, lane = threadIdx.x & 63;
    int mt = b * 4 + wave;
    if (mt >= MT) return;
    gemm_body<128, true>(mt, lane, x, W1b, C8, att_s, att_d, asrc, adst);
    return;
  }
  // scatter: block (chunk, range); range aligns with round-robin XCD dispatch,
  // so each XCD writes only its own 1.6MB csr span (L2-resident, coalescing).
  int b2 = b - GB;
  int range = b2 & 7;
  int e = (b2 >> 3) * 256 + threadIdx.x;
  if (e >= E2) return;
  int dst = (e < EE) ? ei[EE + e] : (e - EE);
  if (dst / RNG != range) return;
  int src = (e < EE) ? ei[e] : dst;
  int rank = atomicAdd(&cnt[dst], 1);
  if (rank < SLOTS) csr_src[(unsigned)dst * SLOTS + rank] = src;
}

// ------- GEMM2 (plain) ----------------------------------------------------------
__global__ void gemm2_kernel(const unsigned short* __restrict__ out1b,
                             const unsigned short* __restrict__ W2b,
                             unsigned char* __restrict__ C8,
                             const float* __restrict__ att_s,
                             const float* __restrict__ att_d,
                             float* __restrict__ asrc, float* __restrict__ adst) {
  int wave = threadIdx.x >> 6, lane = threadIdx.x & 63;
  int mt = blockIdx.x * 4 + wave;
  if (mt >= MT) return;
  gemm_body<64, false>(mt, lane, out1b, W2b, C8, att_s, att_d, asrc, adst);
}

// ------- aggregation: dedup'd weights + den in prologue, pk_fma main loop --------
__global__ void aggregate_kernel(const unsigned char* __restrict__ h8,
                                 const float* __restrict__ asrc,
                                 const float* __restrict__ adst,
                                 const int* __restrict__ cnt,
                                 const int* __restrict__ csr_src,
                                 const float* __restrict__ bias,
                                 unsigned short* __restrict__ outb) {
  int wave = threadIdx.x >> 6, lane = threadIdx.x & 63;
  int node = blockIdx.x * 4 + wave;
  if (node >= NN) return;
  int deg = min(cnt[node], SLOTS);
  int hgrp = lane >> 4;
  int hb = lane & 48;                 // producer-lane base for own head
  float adh = adst[node * 4 + hgrp];
  int src_all = csr_src[(unsigned)node * SLOTS + lane];  // one coalesced 64-wide load
  float wreg[4];
  float den = 0.f;
#pragma unroll
  for (int i = 0; i < 4; ++i) {
    int slot = i * 16 + (lane & 15);
    int s = __shfl(src_all, slot);
    bool valid = slot < deg;
    float xv = asrc[(unsigned)(valid ? s : 0) * 4 + hgrp];
    float w = __expf(lrelu(xv + adh));
    wreg[i] = valid ? w : 0.f;
    den += wreg[i];
  }
#pragma unroll
  for (int o = 1; o < 16; o <<= 1) den += __shfl_xor(den, o);  // sum over j lanes
  const unsigned char* hp = h8 + (unsigned)lane * 4;
  f32x2 a01 = {0.f, 0.f}, a23 = {0.f, 0.f};
  int e = 0;
#pragma unroll
  for (int i = 0; i < 4; ++i) {
    if (e >= deg) break;
    float wcur = wreg[i];
    int bound = min(deg, (i + 1) * 16);
    for (; e + 3 < bound; e += 4) {
      int s0 = __shfl(src_all, e),     s1 = __shfl(src_all, e + 1);
      int s2 = __shfl(src_all, e + 2), s3 = __shfl(src_all, e + 3);
      float w0 = __shfl(wcur, ((e)     & 15) | hb);
      float w1 = __shfl(wcur, ((e + 1) & 15) | hb);
      float w2 = __shfl(wcur, ((e + 2) & 15) | hb);
      float w3 = __shfl(wcur, ((e + 3) & 15) | hb);
      unsigned d0 = *(const unsigned*)(hp + ((unsigned)s0 << 8));
      unsigned d1 = *(const unsigned*)(hp + ((unsigned)s1 << 8));
      unsigned d2 = *(const unsigned*)(hp + ((unsigned)s2 << 8));
      unsigned d3 = *(const unsigned*)(hp + ((unsigned)s3 << 8));
      f32x2 l0 = __builtin_amdgcn_cvt_pk_f32_fp8(d0, false), u0 = __builtin_amdgcn_cvt_pk_f32_fp8(d0, true);
      f32x2 l1 = __builtin_amdgcn_cvt_pk_f32_fp8(d1, false), u1 = __builtin_amdgcn_cvt_pk_f32_fp8(d1, true);
      f32x2 l2 = __builtin_amdgcn_cvt_pk_f32_fp8(d2, false), u2 = __builtin_amdgcn_cvt_pk_f32_fp8(d2, true);
      f32x2 l3 = __builtin_amdgcn_cvt_pk_f32_fp8(d3, false), u3 = __builtin_amdgcn_cvt_pk_f32_fp8(d3, true);
      a01 += l0 * w0; a23 += u0 * w0;
      a01 += l1 * w1; a23 += u1 * w1;
      a01 += l2 * w2; a23 += u2 * w2;
      a01 += l3 * w3; a23 += u3 * w3;
    }
    for (; e < bound; ++e) {
      int s0 = __shfl(src_all, e);
      float w0 = __shfl(wcur, (e & 15) | hb);
      unsigned d0 = *(const unsigned*)(hp + ((unsigned)s0 << 8));
      f32x2 l0 = __builtin_amdgcn_cvt_pk_f32_fp8(d0, false), u0 = __builtin_amdgcn_cvt_pk_f32_fp8(d0, true);
      a01 += l0 * w0; a23 += u0 * w0;
    }
  }
  float inv = 1.f / (den + 1e-16f);
  float r0 = a01.x * inv, r1 = a01.y * inv, r2 = a23.x * inv, r3 = a23.y * inv;
  r0 += __shfl_xor(r0, 16); r0 += __shfl_xor(r0, 32);
  r1 += __shfl_xor(r1, 16); r1 += __shfl_xor(r1, 32);
  r2 += __shfl_xor(r2, 16); r2 += __shfl_xor(r2, 32);
  r3 += __shfl_xor(r3, 16); r3 += __shfl_xor(r3, 32);
  if (lane < 16) {
    float4 bv = *(const float4*)&bias[lane * 4];
    ushort4 o;
    o.x = f2b(sigmoidf(0.25f * r0 + bv.x));
    o.y = f2b(sigmoidf(0.25f * r1 + bv.y));
    o.z = f2b(sigmoidf(0.25f * r2 + bv.z));
    o.w = f2b(sigmoidf(0.25f * r3 + bv.w));
    *(ushort4*)&outb[(size_t)node * 64 + lane * 4] = o;
  }
}

// ------- pool partial with FUSED gate MFMA (per-block, own chunk nodes) ----------
__global__ void pool_partial_kernel(const int* __restrict__ goffs,
                                    const unsigned short* __restrict__ out2b,
                                    const unsigned short* __restrict__ Bg,
                                    const float* __restrict__ gb1,
                                    const float* __restrict__ gamma,
                                    const float* __restrict__ beta,
                                    const float* __restrict__ gw2,
                                    const float* __restrict__ gb2,
                                    float* __restrict__ part_acc,
                                    float* __restrict__ part_den) {
  int b = blockIdx.x, j = blockIdx.y;
  int beg = goffs[b], end = goffs[b + 1];
  int chunk = (end - beg + CH - 1) / CH;
  int cb = beg + j * chunk;
  int ce = min(end, cb + chunk);
  int lane = threadIdx.x & 63, wave = threadIdx.x >> 6;
  int q = lane >> 4, r = lane & 15;
  const float s = rsqrtf(1.f + 1e-5f);
  float gb2v = gb2[0];
  float accv = 0.f, den = 0.f;
  for (int n0 = cb + wave * 16; n0 < ce; n0 += 64) {
    // gate MFMA for nodes n0..n0+15
    f32x4 acc[4] = {};
    int row = n0 + r;
    if (row >= NN) row = NN - 1;
    const unsigned short* Arow = out2b + (size_t)row * 64 + q * 8;
#pragma unroll
    for (int kc = 0; kc < 2; ++kc) {
      bf16x8 a = *(const bf16x8*)(Arow + kc * 32);
#pragma unroll
      for (int nt = 0; nt < 4; ++nt) {
        bf16x8 b8 = *(const bf16x8*)&Bg[(((size_t)nt * 2 + kc) * 64 + lane) * 8];
        acc[nt] = __builtin_amdgcn_mfma_f32_16x16x32_bf16(a, b8, acc[nt], 0, 0, 0);
      }
    }
    float sum[4] = {0.f, 0.f, 0.f, 0.f};
#pragma unroll
    for (int nt = 0; nt < 4; ++nt) {
      int col = nt * 16 + r;
      float off = gb1[col] * gamma[col] * s + beta[col];
      float w2 = gw2[col];
#pragma unroll
      for (int reg = 0; reg < 4; ++reg)
        sum[reg] += fmaxf(acc[nt][reg] + off, 0.f) * w2;
    }
#pragma unroll
    for (int reg = 0; reg < 4; ++reg)
#pragma unroll
      for (int o = 1; o < 16; o <<= 1) sum[reg] += __shfl_xor(sum[reg], o);
    // every lane in q-group now holds g (pre-bias) for node n0+q*4+reg
    float gx[4];
#pragma unroll
    for (int reg = 0; reg < 4; ++reg) {
      int n = n0 + q * 4 + reg;
      gx[reg] = (n < ce) ? __expf(sum[reg] + gb2v) : 0.f;
    }
    // accumulate exp(g[n]) * out2[n, lane] over the wave's 16 nodes
#pragma unroll
    for (int t = 0; t < 16; ++t) {
      int n = n0 + t;
      if (n >= ce) break;
      float gv = __shfl(gx[t & 3], (t >> 2) << 4);
      accv += gv * b2f(out2b[(size_t)n * 64 + lane]);
      den += gv;  // identical on all lanes
    }
  }
  __shared__ float sacc[4][64];
  __shared__ float sden[4];
  sacc[wave][lane] = accv;
  if (lane == 0) sden[wave] = den;
  __syncthreads();
  if (wave == 0) {
    float a = sacc[0][lane] + sacc[1][lane] + sacc[2][lane] + sacc[3][lane];
    part_acc[((size_t)b * CH + j) * 64 + lane] = a;
    if (lane == 0) part_den[b * CH + j] = sden[0] + sden[1] + sden[2] + sden[3];
  }
}

__global__ void pool_final_kernel(const float* __restrict__ part_acc,
                                  const float* __restrict__ part_den,
                                  const float* __restrict__ lw, const float* __restrict__ lb,
                                  float* __restrict__ out) {
  int b = blockIdx.x, lane = threadIdx.x;  // 64 threads
  float a = 0.f;
#pragma unroll
  for (int j = 0; j < CH; ++j) a += part_acc[((size_t)b * CH + j) * 64 + lane];
  float den = (lane < CH) ? part_den[b * CH + lane] : 0.f;
  den = wred(den);
  den = __shfl(den, 0);
  float p = a / (den + 1e-16f);
  float v = wred(p * lw[lane]);
  if (lane == 0) out[b] = sigmoidf(v + lb[0]);
}

extern "C" void kernel_launch(void* const* d_in, const int* in_sizes, int n_in,
                              void* d_out, int out_size, void* d_ws, size_t ws_size,
                              hipStream_t stream) {
  const float* x    = (const float*)d_in[0];
  const int*   ei   = (const int*)d_in[1];
  const int*   batch= (const int*)d_in[2];
  const float* W1   = (const float*)d_in[4];
  const float* as1  = (const float*)d_in[5];
  const float* ad1  = (const float*)d_in[6];
  const float* b1   = (const float*)d_in[7];
  const float* W2   = (const float*)d_in[8];
  const float* as2  = (const float*)d_in[9];
  const float* ad2  = (const float*)d_in[10];
  const float* b2   = (const float*)d_in[11];
  const float* gw1  = (const float*)d_in[12];
  const float* gb1  = (const float*)d_in[13];
  const float* gamma= (const float*)d_in[14];
  const float* beta = (const float*)d_in[15];
  const float* gw2  = (const float*)d_in[16];
  const float* gb2  = (const float*)d_in[17];
  const float* lw   = (const float*)d_in[18];
  const float* lb   = (const float*)d_in[19];
  float* out = (float*)d_out;

  char* ws = (char*)d_ws;
  size_t off = 0;
  auto alloc = [&](size_t bytes) -> void* {
    void* p = ws + off;
    off = (off + bytes + 255) & ~(size_t)255;
    return p;
  };
  unsigned short* W1b    = (unsigned short*)alloc((size_t)128 * 256 * 2);
  unsigned short* W2b    = (unsigned short*)alloc((size_t)64 * 256 * 2);
  unsigned short* Bg     = (unsigned short*)alloc((size_t)64 * 64 * 2);
  unsigned char*  h8     = (unsigned char*)alloc((size_t)NN * 256);
  unsigned short* out1b  = (unsigned short*)alloc((size_t)NN * 64 * 2);
  unsigned short* out2b  = (unsigned short*)alloc((size_t)NN * 64 * 2);
  float*    asrc    = (float*)alloc((size_t)NN * 4 * 4);
  float*    adst    = (float*)alloc((size_t)NN * 4 * 4);
  int*      cnt     = (int*)alloc((size_t)NN * 4);
  int*      csr_src = (int*)alloc((size_t)NN * SLOTS * 4);
  int*      goffs   = (int*)alloc((size_t)(NG + 1) * 4);
  float*    pacc    = (float*)alloc((size_t)NG * CH * 64 * 4);
  float*    pden    = (float*)alloc((size_t)NG * CH * 4);

  const int nodeBlocks = (NN + 3) / 4;       // wave per node, 4 waves/block

  // prep: zero cnt + packs + bounds
  prep_kernel<<<ZERO_NB + 209, 256, 0, stream>>>(W1, W2, gw1, gamma, batch, cnt,
                                                 W1b, W2b, Bg, goffs);

  // Layer 1 GEMM + XCD-partitioned edge scatter in one launch
  gemm1_build_kernel<<<GB + 8 * EDGE_NB, 256, 0, stream>>>(x, W1b, h8, as1, ad1, asrc, adst,
                                                           ei, cnt, csr_src);
  aggregate_kernel<<<nodeBlocks, 256, 0, stream>>>(h8, asrc, adst, cnt, csr_src, b1, out1b);

  // Layer 2
  gemm2_kernel<<<GB, 256, 0, stream>>>(out1b, W2b, h8, as2, ad2, asrc, adst);
  aggregate_kernel<<<nodeBlocks, 256, 0, stream>>>(h8, asrc, adst, cnt, csr_src, b2, out2b);

  // Global attention pooling (gate MFMA fused into partial)
  pool_partial_kernel<<<dim3(NG, CH), 256, 0, stream>>>(goffs, out2b, Bg, gb1, gamma, beta,
                                                        gw2, gb2, pacc, pden);
  pool_final_kernel<<<NG, 64, 0, stream>>>(pacc, pden, lw, lb, out);
}

// Round 18
// 264.908 us; speedup vs baseline: 1.0335x; 1.0335x over previous
//
#include <hip/hip_runtime.h>

// GAT forward (2x GATConv + GlobalAttention pool) for MI355X.
// R17 = R15 (best stable config: single-pass scatter, int csr, dedup'd agg)
// + gate MFMA fused into pool_partial (from R16 — the unimplicated half),
// deleting the gate launch + g round-trip. 7 launches.
// R16's XCD-partitioned scatter REVERTED (8x ei re-scan cost +22MB FETCH > win).

constexpr int NN = 50000;          // nodes
constexpr int EE = 800000;         // edges (without self loops)
constexpr int E2 = EE + NN;        // + self loops
constexpr int NG = 64;             // graphs
constexpr float NEG = 0.2f;       // leaky relu slope
constexpr int MT = NN / 16;        // 3125 m-tiles (NN % 16 == 0)
constexpr int SLOTS = 64;          // CSR slots per node; P(deg>64) ~ 0 (Poisson(16)+1)
constexpr int CH = 16;             // pool chunks per graph
constexpr int GB = (MT + 3) / 4;   // gemm blocks (wave per m-tile, 4 waves/block)
constexpr int EDGE_NB = (E2 + 255) / 256;
constexpr int ZERO_NB = (NN + 255) / 256;   // 196

using bf16x8 = __attribute__((ext_vector_type(8))) __bf16;
using f32x4  = __attribute__((ext_vector_type(4))) float;
using f32x2  = __attribute__((ext_vector_type(2))) float;

__device__ __forceinline__ float wred(float v) {
#pragma unroll
  for (int o = 32; o; o >>= 1) v += __shfl_down(v, o);
  return v;
}
__device__ __forceinline__ float sigmoidf(float v) { return 1.f / (1.f + __expf(-v)); }
__device__ __forceinline__ float lrelu(float v) { return fmaxf(v, NEG * v); }
__device__ __forceinline__ unsigned short f2b(float f) {
  union { float f; unsigned u; } v; v.f = f;
  unsigned r = v.u + 0x7fff + ((v.u >> 16) & 1);
  return (unsigned short)(r >> 16);
}
__device__ __forceinline__ float b2f(unsigned short b) {
  union { unsigned u; float f; } v; v.u = ((unsigned)b) << 16;
  return v.f;
}

// ------- prep: zero cnt + pack W1/W2/gateW + graph bounds (one tiny launch) -------
__global__ void prep_kernel(const float* __restrict__ W1, const float* __restrict__ W2,
                            const float* __restrict__ gw1, const float* __restrict__ gamma,
                            const int* __restrict__ batch, int* __restrict__ cnt,
                            unsigned short* __restrict__ W1b, unsigned short* __restrict__ W2b,
                            unsigned short* __restrict__ Bg, int* __restrict__ goffs) {
  int b = blockIdx.x;
  if (b < ZERO_NB) {
    int i = b * 256 + threadIdx.x;
    if (i < NN) cnt[i] = 0;
    return;
  }
  if (b < ZERO_NB + 128) {  // W1 pack: K=128, KC=4, N=256
    int idx = (b - ZERO_NB) * 256 + threadIdx.x;
    int j = idx & 7, lane = (idx >> 3) & 63, rest = idx >> 9;
    int kc = rest & 3, ntile = rest >> 2;
    W1b[idx] = f2b(W1[(kc * 32 + (lane >> 4) * 8 + j) * 256 + ntile * 16 + (lane & 15)]);
    return;
  }
  if (b < ZERO_NB + 192) {  // W2 pack: K=64, KC=2, N=256
    int idx = (b - ZERO_NB - 128) * 256 + threadIdx.x;
    int j = idx & 7, lane = (idx >> 3) & 63, rest = idx >> 9;
    int kc = rest & 1, ntile = rest >> 1;
    W2b[idx] = f2b(W2[(kc * 32 + (lane >> 4) * 8 + j) * 256 + ntile * 16 + (lane & 15)]);
    return;
  }
  if (b < ZERO_NB + 208) {  // gate W pack: K=64, KC=2, N=64, BN scale folded
    int idx = (b - ZERO_NB - 192) * 256 + threadIdx.x;  // 0..4095
    int j = idx & 7, lane = (idx >> 3) & 63, rest = idx >> 9;
    int kc = rest & 1, nt = rest >> 1;
    int k = kc * 32 + (lane >> 4) * 8 + j;
    int n = nt * 16 + (lane & 15);
    Bg[idx] = f2b(gw1[k * 64 + n] * gamma[n] * rsqrtf(1.f + 1e-5f));
    return;
  }
  // graph bounds (sorted batch, binary search)
  int g = threadIdx.x;
  if (g <= NG) {
    int lo = 0, hi = NN;
    while (lo < hi) {
      int mid = (lo + hi) >> 1;
      if (batch[mid] < g) lo = mid + 1; else hi = mid;
    }
    goffs[g] = lo;
  }
}

// ------- MFMA GEMM body + fused attention; C written fp8-e4m3 -------------------
template <int K, bool A32>
__device__ __forceinline__ void gemm_body(int mt, int lane,
                                          const void* __restrict__ A_raw,
                                          const unsigned short* __restrict__ Bp,
                                          unsigned char* __restrict__ C8,
                                          const float* __restrict__ att_s,
                                          const float* __restrict__ att_d,
                                          float* __restrict__ asrc,
                                          float* __restrict__ adst) {
  constexpr int KC = K / 32;
  int m0 = mt * 16;
  int q = lane >> 4, r = lane & 15;
  f32x4 acc[16] = {};
#pragma unroll
  for (int kc = 0; kc < KC; ++kc) {
    bf16x8 a;
    if constexpr (A32) {
      const float* Arow = (const float*)A_raw + (size_t)(m0 + r) * K + q * 8 + kc * 32;
      float4 f0 = *(const float4*)Arow;
      float4 f1 = *(const float4*)(Arow + 4);
      union { bf16x8 v; unsigned short s[8]; } u;
      u.s[0] = f2b(f0.x); u.s[1] = f2b(f0.y); u.s[2] = f2b(f0.z); u.s[3] = f2b(f0.w);
      u.s[4] = f2b(f1.x); u.s[5] = f2b(f1.y); u.s[6] = f2b(f1.z); u.s[7] = f2b(f1.w);
      a = u.v;
    } else {
      a = *(const bf16x8*)((const unsigned short*)A_raw +
                           (size_t)(m0 + r) * K + q * 8 + kc * 32);
    }
#pragma unroll
    for (int nt = 0; nt < 16; ++nt) {
      bf16x8 b = *(const bf16x8*)&Bp[(((size_t)nt * KC + kc) * 64 + lane) * 8];
      acc[nt] = __builtin_amdgcn_mfma_f32_16x16x32_bf16(a, b, acc[nt], 0, 0, 0);
    }
  }
#pragma unroll
  for (int nt = 0; nt < 16; ++nt) {
    unsigned col = nt * 16 + r;
#pragma unroll
    for (int reg = 0; reg < 4; ++reg) {
      unsigned row = m0 + q * 4 + reg;
      int p = __builtin_amdgcn_cvt_pk_fp8_f32(acc[nt][reg], 0.f, 0, false);
      C8[row * 256u + col] = (unsigned char)(p & 0xff);
    }
  }
  float ps[4][4] = {}, pd[4][4] = {};
#pragma unroll
  for (int head = 0; head < 4; ++head) {
#pragma unroll
    for (int i = 0; i < 4; ++i) {
      float sv = att_s[head * 64 + i * 16 + r];
      float dv = att_d[head * 64 + i * 16 + r];
#pragma unroll
      for (int reg = 0; reg < 4; ++reg) {
        ps[head][reg] += acc[head * 4 + i][reg] * sv;
        pd[head][reg] += acc[head * 4 + i][reg] * dv;
      }
    }
  }
#pragma unroll
  for (int head = 0; head < 4; ++head)
#pragma unroll
    for (int reg = 0; reg < 4; ++reg)
#pragma unroll
      for (int o = 1; o < 16; o <<= 1) {
        ps[head][reg] += __shfl_xor(ps[head][reg], o);
        pd[head][reg] += __shfl_xor(pd[head][reg], o);
      }
  if (r == 0) {
#pragma unroll
    for (int reg = 0; reg < 4; ++reg) {
      int row = m0 + q * 4 + reg;
#pragma unroll
      for (int head = 0; head < 4; ++head) {
        asrc[row * 4 + head] = ps[head][reg];
        adst[row * 4 + head] = pd[head][reg];
      }
    }
  }
}

// ------- GEMM1 + edge-scatter in ONE launch (independent block roles) -----------
__global__ void gemm1_build_kernel(const float* __restrict__ x,
                                   const unsigned short* __restrict__ W1b,
                                   unsigned char* __restrict__ C8,
                                   const float* __restrict__ att_s,
                                   const float* __restrict__ att_d,
                                   float* __restrict__ asrc, float* __restrict__ adst,
                                   const int* __restrict__ ei, int* __restrict__ cnt,
                                   int* __restrict__ csr_src) {
  int b = blockIdx.x;
  if (b < GB) {
    int wave = threadIdx.x >> 6, lane = threadIdx.x & 63;
    int mt = b * 4 + wave;
    if (mt >= MT) return;
    gemm_body<128, true>(mt, lane, x, W1b, C8, att_s, att_d, asrc, adst);
    return;
  }
  int e = (b - GB) * 256 + threadIdx.x;
  if (e >= E2) return;
  int src, dst;
  if (e < EE) { src = ei[e]; dst = ei[EE + e]; }
  else { src = dst = e - EE; }
  int rank = atomicAdd(&cnt[dst], 1);
  if (rank < SLOTS) csr_src[(unsigned)dst * SLOTS + rank] = src;
}

// ------- GEMM2 (plain) ----------------------------------------------------------
__global__ void gemm2_kernel(const unsigned short* __restrict__ out1b,
                             const unsigned short* __restrict__ W2b,
                             unsigned char* __restrict__ C8,
                             const float* __restrict__ att_s,
                             const float* __restrict__ att_d,
                             float* __restrict__ asrc, float* __restrict__ adst) {
  int wave = threadIdx.x >> 6, lane = threadIdx.x & 63;
  int mt = blockIdx.x * 4 + wave;
  if (mt >= MT) return;
  gemm_body<64, false>(mt, lane, out1b, W2b, C8, att_s, att_d, asrc, adst);
}

// ------- aggregation: dedup'd weights + den in prologue, pk_fma main loop --------
__global__ void aggregate_kernel(const unsigned char* __restrict__ h8,
                                 const float* __restrict__ asrc,
                                 const float* __restrict__ adst,
                                 const int* __restrict__ cnt,
                                 const int* __restrict__ csr_src,
                                 const float* __restrict__ bias,
                                 unsigned short* __restrict__ outb) {
  int wave = threadIdx.x >> 6, lane = threadIdx.x & 63;
  int node = blockIdx.x * 4 + wave;
  if (node >= NN) return;
  int deg = min(cnt[node], SLOTS);
  int hgrp = lane >> 4;
  int hb = lane & 48;                 // producer-lane base for own head
  float adh = adst[node * 4 + hgrp];
  int src_all = csr_src[(unsigned)node * SLOTS + lane];  // one coalesced 64-wide load
  float wreg[4];
  float den = 0.f;
#pragma unroll
  for (int i = 0; i < 4; ++i) {
    int slot = i * 16 + (lane & 15);
    int s = __shfl(src_all, slot);
    bool valid = slot < deg;
    float xv = asrc[(unsigned)(valid ? s : 0) * 4 + hgrp];
    float w = __expf(lrelu(xv + adh));
    wreg[i] = valid ? w : 0.f;
    den += wreg[i];
  }
#pragma unroll
  for (int o = 1; o < 16; o <<= 1) den += __shfl_xor(den, o);  // sum over j lanes
  const unsigned char* hp = h8 + (unsigned)lane * 4;
  f32x2 a01 = {0.f, 0.f}, a23 = {0.f, 0.f};
  int e = 0;
#pragma unroll
  for (int i = 0; i < 4; ++i) {
    if (e >= deg) break;
    float wcur = wreg[i];
    int bound = min(deg, (i + 1) * 16);
    for (; e + 3 < bound; e += 4) {
      int s0 = __shfl(src_all, e),     s1 = __shfl(src_all, e + 1);
      int s2 = __shfl(src_all, e + 2), s3 = __shfl(src_all, e + 3);
      float w0 = __shfl(wcur, ((e)     & 15) | hb);
      float w1 = __shfl(wcur, ((e + 1) & 15) | hb);
      float w2 = __shfl(wcur, ((e + 2) & 15) | hb);
      float w3 = __shfl(wcur, ((e + 3) & 15) | hb);
      unsigned d0 = *(const unsigned*)(hp + ((unsigned)s0 << 8));
      unsigned d1 = *(const unsigned*)(hp + ((unsigned)s1 << 8));
      unsigned d2 = *(const unsigned*)(hp + ((unsigned)s2 << 8));
      unsigned d3 = *(const unsigned*)(hp + ((unsigned)s3 << 8));
      f32x2 l0 = __builtin_amdgcn_cvt_pk_f32_fp8(d0, false), u0 = __builtin_amdgcn_cvt_pk_f32_fp8(d0, true);
      f32x2 l1 = __builtin_amdgcn_cvt_pk_f32_fp8(d1, false), u1 = __builtin_amdgcn_cvt_pk_f32_fp8(d1, true);
      f32x2 l2 = __builtin_amdgcn_cvt_pk_f32_fp8(d2, false), u2 = __builtin_amdgcn_cvt_pk_f32_fp8(d2, true);
      f32x2 l3 = __builtin_amdgcn_cvt_pk_f32_fp8(d3, false), u3 = __builtin_amdgcn_cvt_pk_f32_fp8(d3, true);
      a01 += l0 * w0; a23 += u0 * w0;
      a01 += l1 * w1; a23 += u1 * w1;
      a01 += l2 * w2; a23 += u2 * w2;
      a01 += l3 * w3; a23 += u3 * w3;
    }
    for (; e < bound; ++e) {
      int s0 = __shfl(src_all, e);
      float w0 = __shfl(wcur, (e & 15) | hb);
      unsigned d0 = *(const unsigned*)(hp + ((unsigned)s0 << 8));
      f32x2 l0 = __builtin_amdgcn_cvt_pk_f32_fp8(d0, false), u0 = __builtin_amdgcn_cvt_pk_f32_fp8(d0, true);
      a01 += l0 * w0; a23 += u0 * w0;
    }
  }
  float inv = 1.f / (den + 1e-16f);
  float r0 = a01.x * inv, r1 = a01.y * inv, r2 = a23.x * inv, r3 = a23.y * inv;
  r0 += __shfl_xor(r0, 16); r0 += __shfl_xor(r0, 32);
  r1 += __shfl_xor(r1, 16); r1 += __shfl_xor(r1, 32);
  r2 += __shfl_xor(r2, 16); r2 += __shfl_xor(r2, 32);
  r3 += __shfl_xor(r3, 16); r3 += __shfl_xor(r3, 32);
  if (lane < 16) {
    float4 bv = *(const float4*)&bias[lane * 4];
    ushort4 o;
    o.x = f2b(sigmoidf(0.25f * r0 + bv.x));
    o.y = f2b(sigmoidf(0.25f * r1 + bv.y));
    o.z = f2b(sigmoidf(0.25f * r2 + bv.z));
    o.w = f2b(sigmoidf(0.25f * r3 + bv.w));
    *(ushort4*)&outb[(size_t)node * 64 + lane * 4] = o;
  }
}

// ------- pool partial with FUSED gate MFMA (per-block, own chunk nodes) ----------
__global__ void pool_partial_kernel(const int* __restrict__ goffs,
                                    const unsigned short* __restrict__ out2b,
                                    const unsigned short* __restrict__ Bg,
                                    const float* __restrict__ gb1,
                                    const float* __restrict__ gamma,
                                    const float* __restrict__ beta,
                                    const float* __restrict__ gw2,
                                    const float* __restrict__ gb2,
                                    float* __restrict__ part_acc,
                                    float* __restrict__ part_den) {
  int b = blockIdx.x, j = blockIdx.y;
  int beg = goffs[b], end = goffs[b + 1];
  int chunk = (end - beg + CH - 1) / CH;
  int cb = beg + j * chunk;
  int ce = min(end, cb + chunk);
  int lane = threadIdx.x & 63, wave = threadIdx.x >> 6;
  int q = lane >> 4, r = lane & 15;
  const float s = rsqrtf(1.f + 1e-5f);
  float gb2v = gb2[0];
  float accv = 0.f, den = 0.f;
  for (int n0 = cb + wave * 16; n0 < ce; n0 += 64) {
    // gate MFMA for nodes n0..n0+15
    f32x4 acc[4] = {};
    int row = n0 + r;
    if (row >= NN) row = NN - 1;
    const unsigned short* Arow = out2b + (size_t)row * 64 + q * 8;
#pragma unroll
    for (int kc = 0; kc < 2; ++kc) {
      bf16x8 a = *(const bf16x8*)(Arow + kc * 32);
#pragma unroll
      for (int nt = 0; nt < 4; ++nt) {
        bf16x8 b8 = *(const bf16x8*)&Bg[(((size_t)nt * 2 + kc) * 64 + lane) * 8];
        acc[nt] = __builtin_amdgcn_mfma_f32_16x16x32_bf16(a, b8, acc[nt], 0, 0, 0);
      }
    }
    float sum[4] = {0.f, 0.f, 0.f, 0.f};
#pragma unroll
    for (int nt = 0; nt < 4; ++nt) {
      int col = nt * 16 + r;
      float off = gb1[col] * gamma[col] * s + beta[col];
      float w2 = gw2[col];
#pragma unroll
      for (int reg = 0; reg < 4; ++reg)
        sum[reg] += fmaxf(acc[nt][reg] + off, 0.f) * w2;
    }
#pragma unroll
    for (int reg = 0; reg < 4; ++reg)
#pragma unroll
      for (int o = 1; o < 16; o <<= 1) sum[reg] += __shfl_xor(sum[reg], o);
    float gx[4];
#pragma unroll
    for (int reg = 0; reg < 4; ++reg) {
      int n = n0 + q * 4 + reg;
      gx[reg] = (n < ce) ? __expf(sum[reg] + gb2v) : 0.f;
    }
#pragma unroll
    for (int t = 0; t < 16; ++t) {
      int n = n0 + t;
      if (n >= ce) break;
      float gv = __shfl(gx[t & 3], (t >> 2) << 4);
      accv += gv * b2f(out2b[(size_t)n * 64 + lane]);
      den += gv;  // identical on all lanes
    }
  }
  __shared__ float sacc[4][64];
  __shared__ float sden[4];
  sacc[wave][lane] = accv;
  if (lane == 0) sden[wave] = den;
  __syncthreads();
  if (wave == 0) {
    float a = sacc[0][lane] + sacc[1][lane] + sacc[2][lane] + sacc[3][lane];
    part_acc[((size_t)b * CH + j) * 64 + lane] = a;
    if (lane == 0) part_den[b * CH + j] = sden[0] + sden[1] + sden[2] + sden[3];
  }
}

__global__ void pool_final_kernel(const float* __restrict__ part_acc,
                                  const float* __restrict__ part_den,
                                  const float* __restrict__ lw, const float* __restrict__ lb,
                                  float* __restrict__ out) {
  int b = blockIdx.x, lane = threadIdx.x;  // 64 threads
  float a = 0.f;
#pragma unroll
  for (int j = 0; j < CH; ++j) a += part_acc[((size_t)b * CH + j) * 64 + lane];
  float den = (lane < CH) ? part_den[b * CH + lane] : 0.f;
  den = wred(den);
  den = __shfl(den, 0);
  float p = a / (den + 1e-16f);
  float v = wred(p * lw[lane]);
  if (lane == 0) out[b] = sigmoidf(v + lb[0]);
}

extern "C" void kernel_launch(void* const* d_in, const int* in_sizes, int n_in,
                              void* d_out, int out_size, void* d_ws, size_t ws_size,
                              hipStream_t stream) {
  const float* x    = (const float*)d_in[0];
  const int*   ei   = (const int*)d_in[1];
  const int*   batch= (const int*)d_in[2];
  const float* W1   = (const float*)d_in[4];
  const float* as1  = (const float*)d_in[5];
  const float* ad1  = (const float*)d_in[6];
  const float* b1   = (const float*)d_in[7];
  const float* W2   = (const float*)d_in[8];
  const float* as2  = (const float*)d_in[9];
  const float* ad2  = (const float*)d_in[10];
  const float* b2   = (const float*)d_in[11];
  const float* gw1  = (const float*)d_in[12];
  const float* gb1  = (const float*)d_in[13];
  const float* gamma= (const float*)d_in[14];
  const float* beta = (const float*)d_in[15];
  const float* gw2  = (const float*)d_in[16];
  const float* gb2  = (const float*)d_in[17];
  const float* lw   = (const float*)d_in[18];
  const float* lb   = (const float*)d_in[19];
  float* out = (float*)d_out;

  char* ws = (char*)d_ws;
  size_t off = 0;
  auto alloc = [&](size_t bytes) -> void* {
    void* p = ws + off;
    off = (off + bytes + 255) & ~(size_t)255;
    return p;
  };
  unsigned short* W1b    = (unsigned short*)alloc((size_t)128 * 256 * 2);
  unsigned short* W2b    = (unsigned short*)alloc((size_t)64 * 256 * 2);
  unsigned short* Bg     = (unsigned short*)alloc((size_t)64 * 64 * 2);
  unsigned char*  h8     = (unsigned char*)alloc((size_t)NN * 256);
  unsigned short* out1b  = (unsigned short*)alloc((size_t)NN * 64 * 2);
  unsigned short* out2b  = (unsigned short*)alloc((size_t)NN * 64 * 2);
  float*    asrc    = (float*)alloc((size_t)NN * 4 * 4);
  float*    adst    = (float*)alloc((size_t)NN * 4 * 4);
  int*      cnt     = (int*)alloc((size_t)NN * 4);
  int*      csr_src = (int*)alloc((size_t)NN * SLOTS * 4);
  int*      goffs   = (int*)alloc((size_t)(NG + 1) * 4);
  float*    pacc    = (float*)alloc((size_t)NG * CH * 64 * 4);
  float*    pden    = (float*)alloc((size_t)NG * CH * 4);

  const int nodeBlocks = (NN + 3) / 4;       // wave per node, 4 waves/block

  // prep: zero cnt + packs + bounds
  prep_kernel<<<ZERO_NB + 209, 256, 0, stream>>>(W1, W2, gw1, gamma, batch, cnt,
                                                 W1b, W2b, Bg, goffs);

  // Layer 1 GEMM + edge scatter overlapped in one launch
  gemm1_build_kernel<<<GB + EDGE_NB, 256, 0, stream>>>(x, W1b, h8, as1, ad1, asrc, adst,
                                                       ei, cnt, csr_src);
  aggregate_kernel<<<nodeBlocks, 256, 0, stream>>>(h8, asrc, adst, cnt, csr_src, b1, out1b);

  // Layer 2
  gemm2_kernel<<<GB, 256, 0, stream>>>(out1b, W2b, h8, as2, ad2, asrc, adst);
  aggregate_kernel<<<nodeBlocks, 256, 0, stream>>>(h8, asrc, adst, cnt, csr_src, b2, out2b);

  // Global attention pooling (gate MFMA fused into partial)
  pool_partial_kernel<<<dim3(NG, CH), 256, 0, stream>>>(goffs, out2b, Bg, gb1, gamma, beta,
                                                        gw2, gb2, pacc, pden);
  pool_final_kernel<<<NG, 64, 0, stream>>>(pacc, pden, lw, lb, out);
}